// Round 11
// baseline (593.938 us; speedup 1.0000x reference)
//
#include <hip/hip_runtime.h>

static constexpr int B_ = 2, C_ = 96, H_ = 48, W_ = 48, L_ = 2304;
static constexpr int HEADS_ = 8, DK_ = 12, BASEC_ = 32;
static constexpr int DI_ = 192, DS_ = 16, DCONV_ = 4, DTR_ = 6;
static constexpr int NCH_ = 16, CHL_ = 144;   // scan chunks: 16 x 144 = 2304
static constexpr int NMC_ = 12;               // attn key chunks
static constexpr int KC_ = 192;               // keys per chunk (2304/12)
static constexpr int KT2_ = 48;               // keys per LDS tile
static constexpr int QPT_ = 6;                // queries per thread

__device__ __forceinline__ float sigmoidf_(float x){ return 1.f/(1.f+__expf(-x)); }

// ---------------- LayerNorm over channels, output position-major ----------------
__global__ __launch_bounds__(256) void ln_kernel(const float* __restrict__ x,
    const float* __restrict__ nw, const float* __restrict__ nb, float* __restrict__ xn)
{
  __shared__ float tile[96][65];
  __shared__ float muS[64], rsS[64];
  int p0 = blockIdx.x * 64;
  int b  = p0 / L_;
  int hw0 = p0 % L_;
  int tid = threadIdx.x;
  for (int idx = tid; idx < 96*64; idx += 256) {
    int c = idx >> 6, i = idx & 63;
    tile[c][i] = x[((size_t)b*96 + c)*L_ + hw0 + i];
  }
  __syncthreads();
  if (tid < 64) {
    float s = 0.f;
    #pragma unroll 8
    for (int c = 0; c < 96; ++c) s += tile[c][tid];
    float mu = s * (1.f/96.f);
    float v = 0.f;
    #pragma unroll 8
    for (int c = 0; c < 96; ++c) { float d = tile[c][tid]-mu; v += d*d; }
    v *= (1.f/96.f);
    muS[tid] = mu;
    rsS[tid] = rsqrtf(v + 1e-5f);
  }
  __syncthreads();
  for (int idx = tid; idx < 96*64; idx += 256) {
    int i = idx / 96, c = idx % 96;
    float val = (tile[c][i]-muS[i])*rsS[i]*nw[c] + nb[c];
    xn[((size_t)(p0 + i))*96 + c] = val;
  }
}

// ---------------- bilinear resize 12x12 -> 48x48 (half-pixel, clamped) ----------------
__global__ __launch_bounds__(256) void resize_kernel(const float* __restrict__ f, float* __restrict__ o)
{
  int t = blockIdx.x*256 + threadIdx.x;
  if (t >= B_*L_*BASEC_) return;
  int c = t & 31;
  int p = t >> 5;
  int w = p % 48, h = (p/48) % 48, b = p / (48*48);
  const float* a = f + ((size_t)b*32 + c)*144;
  float sh = (h+0.5f)*0.25f - 0.5f;
  float sw = (w+0.5f)*0.25f - 0.5f;
  int h0 = (int)floorf(sh); float fh = sh - (float)h0;
  int w0 = (int)floorf(sw); float fw = sw - (float)w0;
  int h0c = min(max(h0,0),11), h1c = min(max(h0+1,0),11);
  int w0c = min(max(w0,0),11), w1c = min(max(w0+1,0),11);
  float v00 = a[h0c*12+w0c], v01 = a[h0c*12+w1c];
  float v10 = a[h1c*12+w0c], v11 = a[h1c*12+w1c];
  o[t] = (1.f-fh)*((1.f-fw)*v00 + fw*v01) + fh*((1.f-fw)*v10 + fw*v11);
}

// ---------------- generic tiled fp32 GEMM: C[m,n] = sum_k A[m,k]*W[n,k] ----------------
__global__ __launch_bounds__(256) void gemm_k(
    const float* __restrict__ A, int lda,
    const float* __restrict__ W,
    const float* __restrict__ bias,
    float* __restrict__ Co,
    int M, int N, int K,
    int act, int smode,
    const float* __restrict__ resid)
{
  __shared__ __align__(16) float As[16][68];
  __shared__ __align__(16) float Ws[16][68];
  int m0 = blockIdx.y*64, n0 = blockIdx.x*64;
  int tid = threadIdx.x;
  int tm = tid >> 4, tn = tid & 15;
  bool vec = ((K & 15) == 0) && ((lda & 3) == 0);
  float acc[4][4] = {};
  for (int k0 = 0; k0 < K; k0 += 16) {
    if (vec) {
      int row = tid >> 2, kq = (tid & 3) * 4;
      const float4 a4 = *(const float4*)&A[(size_t)(m0+row)*lda + k0 + kq];
      As[kq+0][row]=a4.x; As[kq+1][row]=a4.y; As[kq+2][row]=a4.z; As[kq+3][row]=a4.w;
      float4 w4 = make_float4(0.f,0.f,0.f,0.f);
      int nrow = n0 + row;
      if (nrow < N) w4 = *(const float4*)&W[(size_t)nrow*K + k0 + kq];
      Ws[kq+0][row]=w4.x; Ws[kq+1][row]=w4.y; Ws[kq+2][row]=w4.z; Ws[kq+3][row]=w4.w;
    } else {
      #pragma unroll
      for (int t = 0; t < 4; ++t) {
        int flat = tid + t*256;
        int i = flat >> 4, kk = flat & 15;
        int k = k0 + kk;
        float v = 0.f;
        if (k < K) v = A[(size_t)(m0+i)*lda + k];
        As[kk][i] = v;
      }
      #pragma unroll
      for (int t = 0; t < 4; ++t) {
        int flat = tid + t*256;
        int j = flat >> 4, kk = flat & 15;
        int k = k0 + kk, n = n0 + j;
        float v = 0.f;
        if (k < K && n < N) v = W[(size_t)n*K + k];
        Ws[kk][j] = v;
      }
    }
    __syncthreads();
    #pragma unroll
    for (int kk = 0; kk < 16; ++kk) {
      const float4 av = *(const float4*)&As[kk][tm*4];
      const float4 bv = *(const float4*)&Ws[kk][tn*4];
      float a[4] = {av.x, av.y, av.z, av.w};
      float b[4] = {bv.x, bv.y, bv.z, bv.w};
      #pragma unroll
      for (int i = 0; i < 4; ++i)
        #pragma unroll
        for (int j = 0; j < 4; ++j) acc[i][j] += a[i]*b[j];
    }
    __syncthreads();
  }
  #pragma unroll
  for (int i = 0; i < 4; ++i) {
    int m = m0 + tm*4 + i;
    #pragma unroll
    for (int j = 0; j < 4; ++j) {
      int n = n0 + tn*4 + j;
      if (n < N) {
        float v = acc[i][j];
        if (bias) v += bias[n];
        if (act == 1) v = fmaxf(v, 0.f) + log1pf(__expf(-fabsf(v)));  // softplus
        if (smode == 0) {
          Co[(size_t)m*N + n] = v;
        } else {
          size_t o = ((size_t)(m / L_)*96 + n)*L_ + (m % L_);
          Co[o] = v + resid[o];
        }
      }
    }
  }
}

// ---- attention partial: 6 q/thread (ILP + halved LDS reads), 12 chunks, dbuf LDS ----
__global__ __launch_bounds__(128) void attn_part(const float* __restrict__ q,
    const float* __restrict__ k, const float* __restrict__ v, float* __restrict__ pbuf)
{
  __shared__ __align__(16) float ks[KT2_][12];
  __shared__ __align__(16) float vs[KT2_][12];
  int tid = threadIdx.x;
  int qt = blockIdx.x;              // 0..2  (768 queries each)
  int mc = blockIdx.y;              // 0..11 (192 keys each)
  int h  = blockIdx.z & 7, b = blockIdx.z >> 3;
  int q0 = qt*768 + tid*QPT_;
  const float* qp = q + ((size_t)(b*L_ + q0))*96 + h*12;
  float qv[QPT_][12];
  #pragma unroll
  for (int i = 0; i < QPT_; ++i)
    #pragma unroll
    for (int d = 0; d < 12; ++d)
      qv[i][d] = qp[(size_t)i*96 + d] * 0.28867513459481287f;  // 1/sqrt(12)
  float mx[QPT_], sm[QPT_] = {};
  #pragma unroll
  for (int i = 0; i < QPT_; ++i) mx[i] = -1e30f;
  float acc[QPT_][12] = {};
  const float* kbase = k + ((size_t)b*L_)*96 + h*12;
  const float* vbase = v + ((size_t)b*L_)*96 + h*12;
  int m0 = mc*KC_;
  float4 stg[3];
  // prologue: issue tile-0 loads into registers
  #pragma unroll
  for (int c = 0; c < 3; ++c) {
    int it = tid + c*128;
    if (it < KT2_*3*2) {
      int half = it / (KT2_*3), rem = it % (KT2_*3);
      int r = rem / 3, quad = rem % 3;
      const float* src = (half ? vbase : kbase) + (size_t)(m0 + r)*96 + quad*4;
      stg[c] = *(const float4*)src;
    }
  }
  for (int t0 = 0; t0 < KC_; t0 += KT2_) {
    // write staged registers -> LDS
    #pragma unroll
    for (int c = 0; c < 3; ++c) {
      int it = tid + c*128;
      if (it < KT2_*3*2) {
        int half = it / (KT2_*3), rem = it % (KT2_*3);
        int r = rem / 3, quad = rem % 3;
        float* dst = half ? &vs[r][quad*4] : &ks[r][quad*4];
        *(float4*)dst = stg[c];
      }
    }
    __syncthreads();
    // issue next tile's global loads early (latency hides under compute)
    if (t0 + KT2_ < KC_) {
      #pragma unroll
      for (int c = 0; c < 3; ++c) {
        int it = tid + c*128;
        if (it < KT2_*3*2) {
          int half = it / (KT2_*3), rem = it % (KT2_*3);
          int r = rem / 3, quad = rem % 3;
          const float* src = (half ? vbase : kbase) + (size_t)(m0 + t0 + KT2_ + r)*96 + quad*4;
          stg[c] = *(const float4*)src;
        }
      }
    }
    // compute on current LDS tile
    for (int mi = 0; mi < KT2_; ++mi) {
      float kr[12], vr[12];
      *(float4*)&kr[0] = *(const float4*)&ks[mi][0];
      *(float4*)&kr[4] = *(const float4*)&ks[mi][4];
      *(float4*)&kr[8] = *(const float4*)&ks[mi][8];
      float s[QPT_] = {};
      #pragma unroll
      for (int i = 0; i < QPT_; ++i)
        #pragma unroll
        for (int d = 0; d < 12; ++d) s[i] += qv[i][d]*kr[d];
      *(float4*)&vr[0] = *(const float4*)&vs[mi][0];
      *(float4*)&vr[4] = *(const float4*)&vs[mi][4];
      *(float4*)&vr[8] = *(const float4*)&vs[mi][8];
      #pragma unroll
      for (int i = 0; i < QPT_; ++i) {
        if (s[i] > mx[i] + 12.f) {     // deferred rescale (rare)
          float corr = __expf(mx[i] - s[i]);
          mx[i] = s[i]; sm[i] *= corr;
          #pragma unroll
          for (int d = 0; d < 12; ++d) acc[i][d] *= corr;
        }
        float p = __expf(s[i] - mx[i]);
        sm[i] += p;
        #pragma unroll
        for (int d = 0; d < 12; ++d) acc[i][d] += p*vr[d];
      }
    }
    __syncthreads();   // all waves done reading LDS before next overwrite
  }
  int bh = b*8 + h;
  #pragma unroll
  for (int i = 0; i < QPT_; ++i) {
    float* o = pbuf + (((size_t)bh*NMC_ + mc)*L_ + (q0 + i))*14;
    o[0] = mx[i]; o[1] = sm[i];
    #pragma unroll
    for (int d = 0; d < 12; ++d) o[2+d] = acc[i][d];
  }
}

__global__ __launch_bounds__(256) void attn_comb(const float* __restrict__ pbuf, float* __restrict__ aout)
{
  int t = blockIdx.x*256 + threadIdx.x;
  if (t >= 16*L_) return;
  int l = t % L_, bh = t / L_;
  float gm = -1e30f;
  #pragma unroll
  for (int mc = 0; mc < NMC_; ++mc) {
    const float* r = pbuf + (((size_t)bh*NMC_ + mc)*L_ + l)*14;
    gm = fmaxf(gm, r[0]);
  }
  float tot = 0.f, acc[12] = {};
  #pragma unroll
  for (int mc = 0; mc < NMC_; ++mc) {
    const float* r = pbuf + (((size_t)bh*NMC_ + mc)*L_ + l)*14;
    float w = __expf(r[0] - gm);
    tot += r[1]*w;
    #pragma unroll
    for (int d = 0; d < 12; ++d) acc[d] += r[2+d]*w;
  }
  int b = bh >> 3, h = bh & 7;
  float* o = aout + ((size_t)(b*L_ + l))*96 + h*12;
  float inv = 1.f/tot;
  #pragma unroll
  for (int d = 0; d < 12; ++d) o[d] = acc[d]*inv;
}

// ---------------- gather flipped directions into mamba input (float4 over c) ----------------
__global__ __launch_bounds__(256) void zgather(const float* __restrict__ ot, float* __restrict__ zin)
{
  int t = blockIdx.x*256 + threadIdx.x;
  if (t >= 8*L_*24) return;
  int cq = t % 24; int p = t / 24; int l = p % L_; int bbp = p / L_;
  int dir = bbp / B_, b = bbp % B_;
  int hh = l / 48, ww = l % 48;
  int wsrc = (dir & 1) ? 47 - ww : ww;
  int hsrc = (dir & 2) ? 47 - hh : hh;
  int lsrc = hsrc*48 + wsrc;
  float4 v = *(const float4*)&ot[((size_t)(b*L_) + lsrc)*96 + cq*4];
  *(float4*)&zin[(size_t)p*96 + cq*4] = v;
}

// ---------------- depthwise causal conv (k=4) + bias + silu (float4 over d) ----------------
__global__ __launch_bounds__(256) void conv_kernel(const float* __restrict__ xz,
    const float* __restrict__ cw, const float* __restrict__ cb, float* __restrict__ xc)
{
  int t = blockIdx.x*256 + threadIdx.x;
  if (t >= 8*L_*48) return;
  int dq = t % 48; int p = t / 48; int l = p % L_;
  int d = dq*4;
  float s0 = cb[d], s1 = cb[d+1], s2 = cb[d+2], s3 = cb[d+3];
  #pragma unroll
  for (int kk = 0; kk < 4; ++kk) {
    int ls = l - 3 + kk;
    if (ls >= 0) {
      float4 xv = *(const float4*)&xz[(size_t)(p - 3 + kk)*384 + d];
      s0 += xv.x * cw[(d+0)*4 + kk];
      s1 += xv.y * cw[(d+1)*4 + kk];
      s2 += xv.z * cw[(d+2)*4 + kk];
      s3 += xv.w * cw[(d+3)*4 + kk];
    }
  }
  float4 r;
  r.x = s0 * sigmoidf_(s0);
  r.y = s1 * sigmoidf_(s1);
  r.z = s2 * sigmoidf_(s2);
  r.w = s3 * sigmoidf_(s3);
  *(float4*)&xc[(size_t)p*192 + d] = r;
}

// ---------------- chunked selective scan ----------------
__global__ __launch_bounds__(256) void scan_p1(const float* __restrict__ dtb,
    const float* __restrict__ xcb, const float* __restrict__ xdbl,
    const float* __restrict__ Alog, float* __restrict__ Parr, float* __restrict__ Harr)
{
  int seq = blockIdx.y >> 4;
  int ch  = blockIdx.y & 15;
  int d = blockIdx.x*16 + (threadIdx.x >> 4);
  int n = threadIdx.x & 15;
  float An = -__expf(Alog[d*16 + n]);
  float h = 0.f, P = 1.f;
  size_t base = (size_t)seq * L_ + (size_t)ch * CHL_;
  for (int l = 0; l < CHL_; ++l) {
    size_t p = base + l;
    float dtv = dtb[p*192 + d];
    float xcv = xcb[p*192 + d];
    float Bn  = xdbl[p*38 + 6 + n];
    float dA = __expf(dtv*An);
    h = dA*h + (dtv*xcv)*Bn;
    P *= dA;
  }
  size_t idx = (((size_t)seq*NCH_ + ch)*192 + d)*16 + n;
  Parr[idx] = P; Harr[idx] = h;
}

__global__ __launch_bounds__(256) void scan_p2(const float* __restrict__ Parr,
    const float* __restrict__ Harr, float* __restrict__ Hstart)
{
  int t = blockIdx.x*256 + threadIdx.x;   // (seq, d, n)
  if (t >= 8*192*16) return;
  int n = t & 15; int d = (t >> 4) % 192; int seq = t / (192*16);
  float Hc = 0.f;
  #pragma unroll
  for (int c = 0; c < NCH_; ++c) {
    size_t idx = (((size_t)seq*NCH_ + c)*192 + d)*16 + n;
    Hstart[idx] = Hc;
    Hc = Harr[idx] + Parr[idx]*Hc;
  }
}

__global__ __launch_bounds__(256) void scan_p3(const float* __restrict__ dtb,
    const float* __restrict__ xcb, const float* __restrict__ xdbl,
    const float* __restrict__ xz, const float* __restrict__ Alog,
    const float* __restrict__ Dp, const float* __restrict__ Hstart,
    float* __restrict__ ypre)
{
  int seq = blockIdx.y >> 4;
  int ch  = blockIdx.y & 15;
  int d = blockIdx.x*16 + (threadIdx.x >> 4);
  int n = threadIdx.x & 15;
  float An = -__expf(Alog[d*16 + n]);
  float Dd = Dp[d];
  size_t idx = (((size_t)seq*NCH_ + ch)*192 + d)*16 + n;
  float h = Hstart[idx];
  size_t base = (size_t)seq * L_ + (size_t)ch * CHL_;
  for (int l = 0; l < CHL_; ++l) {
    size_t p = base + l;
    float dtv = dtb[p*192 + d];
    float xcv = xcb[p*192 + d];
    float Bn  = xdbl[p*38 + 6 + n];
    float Cn  = xdbl[p*38 + 22 + n];
    float dA = __expf(dtv*An);
    h = dA*h + (dtv*xcv)*Bn;
    float c = h*Cn;
    c += __shfl_xor(c, 1);
    c += __shfl_xor(c, 2);
    c += __shfl_xor(c, 4);
    c += __shfl_xor(c, 8);
    if (n == 0) {
      float zg = xz[p*384 + 192 + d];
      float yv = c + Dd*xcv;
      yv *= zg * sigmoidf_(zg);
      ypre[p*192 + d] = yv;
    }
  }
}

// ---------------- combine 4 directions (float4 over d, pre-projection) ----------------
__global__ __launch_bounds__(256) void ycomb(const float* __restrict__ ypre, float* __restrict__ ysum)
{
  int t = blockIdx.x*256 + threadIdx.x;
  if (t >= B_*L_*48) return;
  int dq = t % 48; int p = t / 48; int l = p % L_; int b = p / L_;
  int d = dq*4;
  int hh = l / 48, ww = l % 48;
  int l1 = hh*48 + (47 - ww);
  int l2 = (47 - hh)*48 + ww;
  int l3 = (47 - hh)*48 + (47 - ww);
  float4 v0 = *(const float4*)&ypre[(((size_t)(0*B_ + b)*L_ + l ))*192 + d];
  float4 v1 = *(const float4*)&ypre[(((size_t)(1*B_ + b)*L_ + l1))*192 + d];
  float4 v2 = *(const float4*)&ypre[(((size_t)(2*B_ + b)*L_ + l2))*192 + d];
  float4 v3 = *(const float4*)&ypre[(((size_t)(3*B_ + b)*L_ + l3))*192 + d];
  float4 r;
  r.x = (v0.x + v1.x + v2.x + v3.x) * 0.25f;
  r.y = (v0.y + v1.y + v2.y + v3.y) * 0.25f;
  r.z = (v0.z + v1.z + v2.z + v3.z) * 0.25f;
  r.w = (v0.w + v1.w + v2.w + v3.w) * 0.25f;
  *(float4*)&ysum[(size_t)p*192 + d] = r;
}

extern "C" void kernel_launch(void* const* d_in, const int* in_sizes, int n_in,
                              void* d_out, int out_size, void* d_ws, size_t ws_size,
                              hipStream_t stream)
{
  const float* x        = (const float*)d_in[0];
  const float* f_lu     = (const float*)d_in[1];
  const float* norm_w   = (const float*)d_in[2];
  const float* norm_b   = (const float*)d_in[3];
  const float* qproj_w  = (const float*)d_in[4];
  const float* qproj_b  = (const float*)d_in[5];
  const float* iq_w     = (const float*)d_in[6];
  const float* iq_b     = (const float*)d_in[7];
  const float* ik_w     = (const float*)d_in[8];
  const float* ik_b     = (const float*)d_in[9];
  const float* iv_w     = (const float*)d_in[10];
  const float* iv_b     = (const float*)d_in[11];
  const float* io_w     = (const float*)d_in[12];
  const float* io_b     = (const float*)d_in[13];
  const float* m_in_w   = (const float*)d_in[14];
  const float* m_conv_w = (const float*)d_in[15];
  const float* m_conv_b = (const float*)d_in[16];
  const float* m_xproj_w  = (const float*)d_in[17];
  const float* m_dtproj_w = (const float*)d_in[18];
  const float* m_dtproj_b = (const float*)d_in[19];
  const float* m_Alog   = (const float*)d_in[20];
  const float* m_D      = (const float*)d_in[21];
  const float* m_out_w  = (const float*)d_in[22];
  const float* out_w    = (const float*)d_in[23];
  const float* out_b    = (const float*)d_in[24];
  float* ws  = (float*)d_ws;
  float* out = (float*)d_out;

  // workspace layout (floats), lifetime-aliased; peak 21344256 floats (~85 MB)
  float* XN   = ws + 0;         // (B*L, 96)
  float* F48  = ws + 442368;    // (B*L, 32)
  float* FQ   = ws + 589824;    // (B*L, 96)
  float* QT   = ws + 1032192;   // (B*L, 96)
  float* KT   = ws + 1474560;   // (B*L, 96)
  float* VT   = ws + 1916928;   // (B*L, 96)
  float* AOUT = ws + 589824;    // reuse FQ
  float* OT   = ws + 0;         // reuse XN
  float* ZIN  = ws + 2359296;   // (8L, 96)
  float* PART = ws + 4128768;   // attn partials 16*12*L*14 = 6193152 (ends 10321920)
  float* XZ   = ws + 4128768;   // reuse PART region (8L, 384) after attn done
  float* XC   = ws + 11206656;  // (8L, 192)
  float* XDBL = ws + 14745600;  // (8L, 38)
  float* DTB  = ws + 15446016;  // (8L, 192)  ends 18984960
  float* PARR = ws + 18984960;  // (8*16*192*16)
  float* HARR = ws + 19771392;  // (8*16*192*16)
  float* HST  = ws + 20557824;  // (8*16*192*16) ends 21344256
  float* YPRE = ws + 0;         // reuse front region (8L, 192)
  float* YSUM = ws + 3538944;   // (B*L, 192)
  float* CVEC = ws + 4423680;   // (B*L, 96)

  ln_kernel<<<72, 256, 0, stream>>>(x, norm_w, norm_b, XN);
  resize_kernel<<<576, 256, 0, stream>>>(f_lu, F48);
  gemm_k<<<dim3(2,72),  256, 0, stream>>>(F48, 32, qproj_w, qproj_b, FQ, 4608, 96, 32, 0, 0, nullptr);
  gemm_k<<<dim3(2,72),  256, 0, stream>>>(FQ, 96, iq_w, iq_b, QT, 4608, 96, 96, 0, 0, nullptr);
  gemm_k<<<dim3(2,72),  256, 0, stream>>>(XN, 96, ik_w, ik_b, KT, 4608, 96, 96, 0, 0, nullptr);
  gemm_k<<<dim3(2,72),  256, 0, stream>>>(XN, 96, iv_w, iv_b, VT, 4608, 96, 96, 0, 0, nullptr);
  attn_part<<<dim3(3,NMC_,16), 128, 0, stream>>>(QT, KT, VT, PART);
  attn_comb<<<144, 256, 0, stream>>>(PART, AOUT);
  gemm_k<<<dim3(2,72),  256, 0, stream>>>(AOUT, 96, io_w, io_b, OT, 4608, 96, 96, 0, 0, nullptr);
  zgather<<<1728, 256, 0, stream>>>(OT, ZIN);
  gemm_k<<<dim3(6,288), 256, 0, stream>>>(ZIN, 96, m_in_w, nullptr, XZ, 18432, 384, 96, 0, 0, nullptr);
  conv_kernel<<<3456, 256, 0, stream>>>(XZ, m_conv_w, m_conv_b, XC);
  gemm_k<<<dim3(1,288), 256, 0, stream>>>(XC, 192, m_xproj_w, nullptr, XDBL, 18432, 38, 192, 0, 0, nullptr);
  gemm_k<<<dim3(3,288), 256, 0, stream>>>(XDBL, 38, m_dtproj_w, m_dtproj_b, DTB, 18432, 192, 6, 1, 0, nullptr);
  scan_p1<<<dim3(12,128), 256, 0, stream>>>(DTB, XC, XDBL, m_Alog, PARR, HARR);
  scan_p2<<<96, 256, 0, stream>>>(PARR, HARR, HST);
  scan_p3<<<dim3(12,128), 256, 0, stream>>>(DTB, XC, XDBL, XZ, m_Alog, m_D, HST, YPRE);
  ycomb<<<864, 256, 0, stream>>>(YPRE, YSUM);
  gemm_k<<<dim3(2,72),  256, 0, stream>>>(YSUM, 192, m_out_w, nullptr, CVEC, 4608, 96, 192, 0, 0, nullptr);
  gemm_k<<<dim3(2,72),  256, 0, stream>>>(CVEC, 96, out_w, out_b, out, 4608, 96, 96, 0, 1, x);
}

// Round 14
// 496.161 us; speedup vs baseline: 1.1971x; 1.1971x over previous
//
#include <hip/hip_runtime.h>

static constexpr int B_ = 2, C_ = 96, H_ = 48, W_ = 48, L_ = 2304;
static constexpr int HEADS_ = 8, DK_ = 12, BASEC_ = 32;
static constexpr int DI_ = 192, DS_ = 16, DCONV_ = 4, DTR_ = 6;
static constexpr int NCH_ = 16, CHL_ = 144;   // scan chunks: 16 x 144 = 2304

using f16x8 = __attribute__((ext_vector_type(8))) _Float16;
using f32x4 = __attribute__((ext_vector_type(4))) float;

__device__ __forceinline__ float sigmoidf_(float x){ return 1.f/(1.f+__expf(-x)); }

// ---------------- LayerNorm over channels, output position-major ----------------
__global__ __launch_bounds__(256) void ln_kernel(const float* __restrict__ x,
    const float* __restrict__ nw, const float* __restrict__ nb, float* __restrict__ xn)
{
  __shared__ float tile[96][65];
  __shared__ float muS[64], rsS[64];
  int p0 = blockIdx.x * 64;
  int b  = p0 / L_;
  int hw0 = p0 % L_;
  int tid = threadIdx.x;
  for (int idx = tid; idx < 96*64; idx += 256) {
    int c = idx >> 6, i = idx & 63;
    tile[c][i] = x[((size_t)b*96 + c)*L_ + hw0 + i];
  }
  __syncthreads();
  if (tid < 64) {
    float s = 0.f;
    #pragma unroll 8
    for (int c = 0; c < 96; ++c) s += tile[c][tid];
    float mu = s * (1.f/96.f);
    float v = 0.f;
    #pragma unroll 8
    for (int c = 0; c < 96; ++c) { float d = tile[c][tid]-mu; v += d*d; }
    v *= (1.f/96.f);
    muS[tid] = mu;
    rsS[tid] = rsqrtf(v + 1e-5f);
  }
  __syncthreads();
  for (int idx = tid; idx < 96*64; idx += 256) {
    int i = idx / 96, c = idx % 96;
    float val = (tile[c][i]-muS[i])*rsS[i]*nw[c] + nb[c];
    xn[((size_t)(p0 + i))*96 + c] = val;
  }
}

// ---------------- bilinear resize 12x12 -> 48x48 (half-pixel, clamped) ----------------
__global__ __launch_bounds__(256) void resize_kernel(const float* __restrict__ f, float* __restrict__ o)
{
  int t = blockIdx.x*256 + threadIdx.x;
  if (t >= B_*L_*BASEC_) return;
  int c = t & 31;
  int p = t >> 5;
  int w = p % 48, h = (p/48) % 48, b = p / (48*48);
  const float* a = f + ((size_t)b*32 + c)*144;
  float sh = (h+0.5f)*0.25f - 0.5f;
  float sw = (w+0.5f)*0.25f - 0.5f;
  int h0 = (int)floorf(sh); float fh = sh - (float)h0;
  int w0 = (int)floorf(sw); float fw = sw - (float)w0;
  int h0c = min(max(h0,0),11), h1c = min(max(h0+1,0),11);
  int w0c = min(max(w0,0),11), w1c = min(max(w0+1,0),11);
  float v00 = a[h0c*12+w0c], v01 = a[h0c*12+w1c];
  float v10 = a[h1c*12+w0c], v11 = a[h1c*12+w1c];
  o[t] = (1.f-fh)*((1.f-fw)*v00 + fw*v01) + fh*((1.f-fw)*v10 + fw*v11);
}

// ---------------- generic tiled fp32 GEMM: C[m,n] = sum_k A[m,k]*W[n,k] ----------------
__global__ __launch_bounds__(256) void gemm_k(
    const float* __restrict__ A, int lda,
    const float* __restrict__ W,
    const float* __restrict__ bias,
    float* __restrict__ Co,
    int M, int N, int K,
    int act, int smode,
    const float* __restrict__ resid)
{
  __shared__ __align__(16) float As[16][68];
  __shared__ __align__(16) float Ws[16][68];
  int m0 = blockIdx.y*64, n0 = blockIdx.x*64;
  int tid = threadIdx.x;
  int tm = tid >> 4, tn = tid & 15;
  bool vec = ((K & 15) == 0) && ((lda & 3) == 0);
  float acc[4][4] = {};
  for (int k0 = 0; k0 < K; k0 += 16) {
    if (vec) {
      int row = tid >> 2, kq = (tid & 3) * 4;
      const float4 a4 = *(const float4*)&A[(size_t)(m0+row)*lda + k0 + kq];
      As[kq+0][row]=a4.x; As[kq+1][row]=a4.y; As[kq+2][row]=a4.z; As[kq+3][row]=a4.w;
      float4 w4 = make_float4(0.f,0.f,0.f,0.f);
      int nrow = n0 + row;
      if (nrow < N) w4 = *(const float4*)&W[(size_t)nrow*K + k0 + kq];
      Ws[kq+0][row]=w4.x; Ws[kq+1][row]=w4.y; Ws[kq+2][row]=w4.z; Ws[kq+3][row]=w4.w;
    } else {
      #pragma unroll
      for (int t = 0; t < 4; ++t) {
        int flat = tid + t*256;
        int i = flat >> 4, kk = flat & 15;
        int k = k0 + kk;
        float v = 0.f;
        if (k < K) v = A[(size_t)(m0+i)*lda + k];
        As[kk][i] = v;
      }
      #pragma unroll
      for (int t = 0; t < 4; ++t) {
        int flat = tid + t*256;
        int j = flat >> 4, kk = flat & 15;
        int k = k0 + kk, n = n0 + j;
        float v = 0.f;
        if (k < K && n < N) v = W[(size_t)n*K + k];
        Ws[kk][j] = v;
      }
    }
    __syncthreads();
    #pragma unroll
    for (int kk = 0; kk < 16; ++kk) {
      const float4 av = *(const float4*)&As[kk][tm*4];
      const float4 bv = *(const float4*)&Ws[kk][tn*4];
      float a[4] = {av.x, av.y, av.z, av.w};
      float b[4] = {bv.x, bv.y, bv.z, bv.w};
      #pragma unroll
      for (int i = 0; i < 4; ++i)
        #pragma unroll
        for (int j = 0; j < 4; ++j) acc[i][j] += a[i]*b[j];
    }
    __syncthreads();
  }
  #pragma unroll
  for (int i = 0; i < 4; ++i) {
    int m = m0 + tm*4 + i;
    #pragma unroll
    for (int j = 0; j < 4; ++j) {
      int n = n0 + tn*4 + j;
      if (n < N) {
        float v = acc[i][j];
        if (bias) v += bias[n];
        if (act == 1) v = fmaxf(v, 0.f) + log1pf(__expf(-fabsf(v)));  // softplus
        if (smode == 0) {
          Co[(size_t)m*N + n] = v;
        } else {
          size_t o = ((size_t)(m / L_)*96 + n)*L_ + (m % L_);
          Co[o] = v + resid[o];
        }
      }
    }
  }
}

// ---------------- convert Q,K,V to fp16 MFMA layouts ----------------
// Qh/Kh: [bh][L][32] (dk padded 12->32, Q pre-scaled by 1/sqrt(12))
// VTh:   [bh][16][L] (transposed, d padded 12->16)
__global__ __launch_bounds__(64) void qkv2h(const float* __restrict__ QT,
    const float* __restrict__ KT, const float* __restrict__ VT,
    _Float16* __restrict__ Qh, _Float16* __restrict__ Kh, _Float16* __restrict__ VTh)
{
  int bh = blockIdx.x;                  // 0..15
  int l  = blockIdx.y*64 + threadIdx.x; // 0..2303
  int b = bh >> 3, h = bh & 7;
  size_t src = ((size_t)(b*L_ + l))*96 + h*12;
  alignas(16) _Float16 qrow[32];
  alignas(16) _Float16 krow[32];
  #pragma unroll
  for (int d = 0; d < 12; ++d) {
    qrow[d] = (_Float16)(QT[src+d] * 0.28867513459481287f);
    krow[d] = (_Float16)KT[src+d];
  }
  #pragma unroll
  for (int d = 12; d < 32; ++d) { qrow[d] = (_Float16)0.f; krow[d] = (_Float16)0.f; }
  _Float16* qdst = Qh + ((size_t)(bh*L_ + l))*32;
  _Float16* kdst = Kh + ((size_t)(bh*L_ + l))*32;
  #pragma unroll
  for (int t = 0; t < 4; ++t) {
    *(uint4*)(qdst + t*8) = *(const uint4*)&qrow[t*8];
    *(uint4*)(kdst + t*8) = *(const uint4*)&krow[t*8];
  }
  #pragma unroll
  for (int d = 0; d < 12; ++d)
    VTh[((size_t)(bh*16 + d))*L_ + l] = (_Float16)VT[src+d];
  #pragma unroll
  for (int d = 12; d < 16; ++d)
    VTh[((size_t)(bh*16 + d))*L_ + l] = (_Float16)0.f;
}

// ---------------- MFMA flash attention: one wave per (bh, 16-query tile) ----------------
// S^T = mfma(K_frag, Q_frag) with permuted K rows so P^T lands exactly in PV's B-frag.
// Online softmax per q (q = lane&15): 3 in-lane max + 2 shfl; defer-max THR=10.
__global__ __launch_bounds__(64) void attn_mfma(
    const _Float16* __restrict__ Qh, const _Float16* __restrict__ Kh,
    const _Float16* __restrict__ VTh, float* __restrict__ aout)
{
  int lane = threadIdx.x;
  int qt = blockIdx.x;      // 0..143
  int bh = blockIdx.y;      // 0..15
  int a = lane & 15, g = lane >> 4;
  const f16x8 qf = *(const f16x8*)(Qh + ((size_t)(bh*L_ + qt*16 + a))*32 + g*8);
  f32x4 o = {0.f,0.f,0.f,0.f};
  float m = -1e30f, s = 0.f;
  const _Float16* kb = Kh + (size_t)bh*L_*32;
  const _Float16* vb = VTh + ((size_t)(bh*16 + a))*L_;
  int krow0 = 8*(a>>2) + (a&3);   // permuted row: makes P^T frag == PV B-frag layout
  for (int kt = 0; kt < L_; kt += 32) {
    const f16x8 kf0 = *(const f16x8*)(kb + (size_t)(kt + krow0    )*32 + g*8);
    const f16x8 kf1 = *(const f16x8*)(kb + (size_t)(kt + krow0 + 4)*32 + g*8);
    f32x4 z = {0.f,0.f,0.f,0.f};
    f32x4 st0 = __builtin_amdgcn_mfma_f32_16x16x32_f16(kf0, qf, z, 0, 0, 0);
    f32x4 st1 = __builtin_amdgcn_mfma_f32_16x16x32_f16(kf1, qf, z, 0, 0, 0);
    // st0[r] = S[key=kt+8g+r][q=a], st1[r] = S[key=kt+8g+4+r][q=a]
    float tm = fmaxf(fmaxf(fmaxf(st0[0],st0[1]),fmaxf(st0[2],st0[3])),
                     fmaxf(fmaxf(st1[0],st1[1]),fmaxf(st1[2],st1[3])));
    tm = fmaxf(tm, __shfl_xor(tm, 16));
    tm = fmaxf(tm, __shfl_xor(tm, 32));
    if (!__all(tm <= m + 10.f)) {
      float nm = fmaxf(m, tm);
      float corr = __expf(m - nm);
      s *= corr;
      o[0]*=corr; o[1]*=corr; o[2]*=corr; o[3]*=corr;
      m = nm;
    }
    float p0=__expf(st0[0]-m), p1=__expf(st0[1]-m), p2=__expf(st0[2]-m), p3=__expf(st0[3]-m);
    float p4=__expf(st1[0]-m), p5=__expf(st1[1]-m), p6=__expf(st1[2]-m), p7=__expf(st1[3]-m);
    s += (p0+p1)+(p2+p3)+(p4+p5)+(p6+p7);
    f16x8 pf;
    pf[0]=(_Float16)p0; pf[1]=(_Float16)p1; pf[2]=(_Float16)p2; pf[3]=(_Float16)p3;
    pf[4]=(_Float16)p4; pf[5]=(_Float16)p5; pf[6]=(_Float16)p6; pf[7]=(_Float16)p7;
    const f16x8 vf = *(const f16x8*)(vb + kt + g*8);
    o = __builtin_amdgcn_mfma_f32_16x16x32_f16(vf, pf, o, 0, 0, 0);
  }
  s += __shfl_xor(s, 16);
  s += __shfl_xor(s, 32);
  float inv = 1.f / s;
  if (g < 3) {                         // O rows d = 4g..4g+3, d<12 real
    int b = bh >> 3, h = bh & 7;
    float4 r; r.x = o[0]*inv; r.y = o[1]*inv; r.z = o[2]*inv; r.w = o[3]*inv;
    *(float4*)&aout[((size_t)(b*L_ + qt*16 + a))*96 + h*12 + g*4] = r;
  }
}

// ---------------- gather flipped directions into mamba input (float4 over c) ----------------
__global__ __launch_bounds__(256) void zgather(const float* __restrict__ ot, float* __restrict__ zin)
{
  int t = blockIdx.x*256 + threadIdx.x;
  if (t >= 8*L_*24) return;
  int cq = t % 24; int p = t / 24; int l = p % L_; int bbp = p / L_;
  int dir = bbp / B_, b = bbp % B_;
  int hh = l / 48, ww = l % 48;
  int wsrc = (dir & 1) ? 47 - ww : ww;
  int hsrc = (dir & 2) ? 47 - hh : hh;
  int lsrc = hsrc*48 + wsrc;
  float4 v = *(const float4*)&ot[((size_t)(b*L_) + lsrc)*96 + cq*4];
  *(float4*)&zin[(size_t)p*96 + cq*4] = v;
}

// ---------------- depthwise causal conv (k=4) + bias + silu (float4 over d) ----------------
__global__ __launch_bounds__(256) void conv_kernel(const float* __restrict__ xz,
    const float* __restrict__ cw, const float* __restrict__ cb, float* __restrict__ xc)
{
  int t = blockIdx.x*256 + threadIdx.x;
  if (t >= 8*L_*48) return;
  int dq = t % 48; int p = t / 48; int l = p % L_;
  int d = dq*4;
  float s0 = cb[d], s1 = cb[d+1], s2 = cb[d+2], s3 = cb[d+3];
  #pragma unroll
  for (int kk = 0; kk < 4; ++kk) {
    int ls = l - 3 + kk;
    if (ls >= 0) {
      float4 xv = *(const float4*)&xz[(size_t)(p - 3 + kk)*384 + d];
      s0 += xv.x * cw[(d+0)*4 + kk];
      s1 += xv.y * cw[(d+1)*4 + kk];
      s2 += xv.z * cw[(d+2)*4 + kk];
      s3 += xv.w * cw[(d+3)*4 + kk];
    }
  }
  float4 r;
  r.x = s0 * sigmoidf_(s0);
  r.y = s1 * sigmoidf_(s1);
  r.z = s2 * sigmoidf_(s2);
  r.w = s3 * sigmoidf_(s3);
  *(float4*)&xc[(size_t)p*192 + d] = r;
}

// ---------------- chunked selective scan ----------------
__global__ __launch_bounds__(256) void scan_p1(const float* __restrict__ dtb,
    const float* __restrict__ xcb, const float* __restrict__ xdbl,
    const float* __restrict__ Alog, float* __restrict__ Parr, float* __restrict__ Harr)
{
  int seq = blockIdx.y >> 4;
  int ch  = blockIdx.y & 15;
  int d = blockIdx.x*16 + (threadIdx.x >> 4);
  int n = threadIdx.x & 15;
  float An = -__expf(Alog[d*16 + n]);
  float h = 0.f, P = 1.f;
  size_t base = (size_t)seq * L_ + (size_t)ch * CHL_;
  for (int l = 0; l < CHL_; ++l) {
    size_t p = base + l;
    float dtv = dtb[p*192 + d];
    float xcv = xcb[p*192 + d];
    float Bn  = xdbl[p*38 + 6 + n];
    float dA = __expf(dtv*An);
    h = dA*h + (dtv*xcv)*Bn;
    P *= dA;
  }
  size_t idx = (((size_t)seq*NCH_ + ch)*192 + d)*16 + n;
  Parr[idx] = P; Harr[idx] = h;
}

__global__ __launch_bounds__(256) void scan_p2(const float* __restrict__ Parr,
    const float* __restrict__ Harr, float* __restrict__ Hstart)
{
  int t = blockIdx.x*256 + threadIdx.x;   // (seq, d, n)
  if (t >= 8*192*16) return;
  int n = t & 15; int d = (t >> 4) % 192; int seq = t / (192*16);
  float Hc = 0.f;
  #pragma unroll
  for (int c = 0; c < NCH_; ++c) {
    size_t idx = (((size_t)seq*NCH_ + c)*192 + d)*16 + n;
    Hstart[idx] = Hc;
    Hc = Harr[idx] + Parr[idx]*Hc;
  }
}

__global__ __launch_bounds__(256) void scan_p3(const float* __restrict__ dtb,
    const float* __restrict__ xcb, const float* __restrict__ xdbl,
    const float* __restrict__ xz, const float* __restrict__ Alog,
    const float* __restrict__ Dp, const float* __restrict__ Hstart,
    float* __restrict__ ypre)
{
  int seq = blockIdx.y >> 4;
  int ch  = blockIdx.y & 15;
  int d = blockIdx.x*16 + (threadIdx.x >> 4);
  int n = threadIdx.x & 15;
  float An = -__expf(Alog[d*16 + n]);
  float Dd = Dp[d];
  size_t idx = (((size_t)seq*NCH_ + ch)*192 + d)*16 + n;
  float h = Hstart[idx];
  size_t base = (size_t)seq * L_ + (size_t)ch * CHL_;
  for (int l = 0; l < CHL_; ++l) {
    size_t p = base + l;
    float dtv = dtb[p*192 + d];
    float xcv = xcb[p*192 + d];
    float Bn  = xdbl[p*38 + 6 + n];
    float Cn  = xdbl[p*38 + 22 + n];
    float dA = __expf(dtv*An);
    h = dA*h + (dtv*xcv)*Bn;
    float c = h*Cn;
    c += __shfl_xor(c, 1);
    c += __shfl_xor(c, 2);
    c += __shfl_xor(c, 4);
    c += __shfl_xor(c, 8);
    if (n == 0) {
      float zg = xz[p*384 + 192 + d];
      float yv = c + Dd*xcv;
      yv *= zg * sigmoidf_(zg);
      ypre[p*192 + d] = yv;
    }
  }
}

// ---------------- combine 4 directions (float4 over d, pre-projection) ----------------
__global__ __launch_bounds__(256) void ycomb(const float* __restrict__ ypre, float* __restrict__ ysum)
{
  int t = blockIdx.x*256 + threadIdx.x;
  if (t >= B_*L_*48) return;
  int dq = t % 48; int p = t / 48; int l = p % L_; int b = p / L_;
  int d = dq*4;
  int hh = l / 48, ww = l % 48;
  int l1 = hh*48 + (47 - ww);
  int l2 = (47 - hh)*48 + ww;
  int l3 = (47 - hh)*48 + (47 - ww);
  float4 v0 = *(const float4*)&ypre[(((size_t)(0*B_ + b)*L_ + l ))*192 + d];
  float4 v1 = *(const float4*)&ypre[(((size_t)(1*B_ + b)*L_ + l1))*192 + d];
  float4 v2 = *(const float4*)&ypre[(((size_t)(2*B_ + b)*L_ + l2))*192 + d];
  float4 v3 = *(const float4*)&ypre[(((size_t)(3*B_ + b)*L_ + l3))*192 + d];
  float4 r;
  r.x = (v0.x + v1.x + v2.x + v3.x) * 0.25f;
  r.y = (v0.y + v1.y + v2.y + v3.y) * 0.25f;
  r.z = (v0.z + v1.z + v2.z + v3.z) * 0.25f;
  r.w = (v0.w + v1.w + v2.w + v3.w) * 0.25f;
  *(float4*)&ysum[(size_t)p*192 + d] = r;
}

extern "C" void kernel_launch(void* const* d_in, const int* in_sizes, int n_in,
                              void* d_out, int out_size, void* d_ws, size_t ws_size,
                              hipStream_t stream)
{
  const float* x        = (const float*)d_in[0];
  const float* f_lu     = (const float*)d_in[1];
  const float* norm_w   = (const float*)d_in[2];
  const float* norm_b   = (const float*)d_in[3];
  const float* qproj_w  = (const float*)d_in[4];
  const float* qproj_b  = (const float*)d_in[5];
  const float* iq_w     = (const float*)d_in[6];
  const float* iq_b     = (const float*)d_in[7];
  const float* ik_w     = (const float*)d_in[8];
  const float* ik_b     = (const float*)d_in[9];
  const float* iv_w     = (const float*)d_in[10];
  const float* iv_b     = (const float*)d_in[11];
  const float* io_w     = (const float*)d_in[12];
  const float* io_b     = (const float*)d_in[13];
  const float* m_in_w   = (const float*)d_in[14];
  const float* m_conv_w = (const float*)d_in[15];
  const float* m_conv_b = (const float*)d_in[16];
  const float* m_xproj_w  = (const float*)d_in[17];
  const float* m_dtproj_w = (const float*)d_in[18];
  const float* m_dtproj_b = (const float*)d_in[19];
  const float* m_Alog   = (const float*)d_in[20];
  const float* m_D      = (const float*)d_in[21];
  const float* m_out_w  = (const float*)d_in[22];
  const float* out_w    = (const float*)d_in[23];
  const float* out_b    = (const float*)d_in[24];
  float* ws  = (float*)d_ws;
  float* out = (float*)d_out;

  // workspace layout (floats), lifetime-aliased; peak 21344256 floats (~85 MB)
  float* XN   = ws + 0;         // (B*L, 96)
  float* F48  = ws + 442368;    // (B*L, 32)
  float* FQ   = ws + 589824;    // (B*L, 96)
  float* QT   = ws + 1032192;   // (B*L, 96)
  float* KT   = ws + 1474560;   // (B*L, 96)
  float* VT   = ws + 1916928;   // (B*L, 96)
  float* AOUT = ws + 589824;    // reuse FQ (dead after QT gemm)
  float* OT   = ws + 0;         // reuse XN
  float* ZIN  = ws + 2359296;   // (8L, 96)
  // fp16 attn buffers live in the region XZ reuses later (disjoint lifetimes)
  _Float16* QH  = (_Float16*)(ws + 4128768);  // [16][L][32] = 1179648 floats
  _Float16* KH  = (_Float16*)(ws + 5308416);  // [16][L][32]
  _Float16* VTH = (_Float16*)(ws + 6488064);  // [16][16][L] = 294912 floats
  float* XZ   = ws + 4128768;   // (8L, 384) after attn done
  float* XC   = ws + 11206656;  // (8L, 192)
  float* XDBL = ws + 14745600;  // (8L, 38)
  float* DTB  = ws + 15446016;  // (8L, 192)  ends 18984960
  float* PARR = ws + 18984960;  // (8*16*192*16)
  float* HARR = ws + 19771392;  // (8*16*192*16)
  float* HST  = ws + 20557824;  // (8*16*192*16) ends 21344256
  float* YPRE = ws + 0;         // reuse front region (8L, 192)
  float* YSUM = ws + 3538944;   // (B*L, 192)
  float* CVEC = ws + 4423680;   // (B*L, 96)

  ln_kernel<<<72, 256, 0, stream>>>(x, norm_w, norm_b, XN);
  resize_kernel<<<576, 256, 0, stream>>>(f_lu, F48);
  gemm_k<<<dim3(2,72),  256, 0, stream>>>(F48, 32, qproj_w, qproj_b, FQ, 4608, 96, 32, 0, 0, nullptr);
  gemm_k<<<dim3(2,72),  256, 0, stream>>>(FQ, 96, iq_w, iq_b, QT, 4608, 96, 96, 0, 0, nullptr);
  gemm_k<<<dim3(2,72),  256, 0, stream>>>(XN, 96, ik_w, ik_b, KT, 4608, 96, 96, 0, 0, nullptr);
  gemm_k<<<dim3(2,72),  256, 0, stream>>>(XN, 96, iv_w, iv_b, VT, 4608, 96, 96, 0, 0, nullptr);
  qkv2h<<<dim3(16,36), 64, 0, stream>>>(QT, KT, VT, QH, KH, VTH);
  attn_mfma<<<dim3(144,16), 64, 0, stream>>>(QH, KH, VTH, AOUT);
  gemm_k<<<dim3(2,72),  256, 0, stream>>>(AOUT, 96, io_w, io_b, OT, 4608, 96, 96, 0, 0, nullptr);
  zgather<<<1728, 256, 0, stream>>>(OT, ZIN);
  gemm_k<<<dim3(6,288), 256, 0, stream>>>(ZIN, 96, m_in_w, nullptr, XZ, 18432, 384, 96, 0, 0, nullptr);
  conv_kernel<<<3456, 256, 0, stream>>>(XZ, m_conv_w, m_conv_b, XC);
  gemm_k<<<dim3(1,288), 256, 0, stream>>>(XC, 192, m_xproj_w, nullptr, XDBL, 18432, 38, 192, 0, 0, nullptr);
  gemm_k<<<dim3(3,288), 256, 0, stream>>>(XDBL, 38, m_dtproj_w, m_dtproj_b, DTB, 18432, 192, 6, 1, 0, nullptr);
  scan_p1<<<dim3(12,128), 256, 0, stream>>>(DTB, XC, XDBL, m_Alog, PARR, HARR);
  scan_p2<<<96, 256, 0, stream>>>(PARR, HARR, HST);
  scan_p3<<<dim3(12,128), 256, 0, stream>>>(DTB, XC, XDBL, XZ, m_Alog, m_D, HST, YPRE);
  ycomb<<<864, 256, 0, stream>>>(YPRE, YSUM);
  gemm_k<<<dim3(2,72),  256, 0, stream>>>(YSUM, 192, m_out_w, nullptr, CVEC, 4608, 96, 192, 0, 0, nullptr);
  gemm_k<<<dim3(2,72),  256, 0, stream>>>(CVEC, 96, out_w, out_b, out, 4608, 96, 96, 0, 1, x);
}